// Round 6
// baseline (3530.305 us; speedup 1.0000x reference)
//
#include <hip/hip_runtime.h>
#include <cstdint>

// DA_RNN particle filter, B=128 T=32 H=256 K=32.
// Round 6: one dispatch/step, grid 512 x 1024 thr (khalf in [0,4), 8 rows/block),
// __launch_bounds__(1024,8) -> VGPR<=64 -> 2 blocks/CU (32 waves) for GEMM latency
// hiding. Head GEMVs software-pipelined (16 loads in flight, chain order intact),
// Gumbel generation parallelized (pure function, identical bits), serial sums via
// float4 LDS loads. ALL fp chains operand-for-operand the round-1 bit-exact order.

#define Bn 128
#define Tn 32
#define Hn 256
#define Kn 32

__host__ __device__ inline void tf2x32(uint32_t k0, uint32_t k1, uint32_t x0, uint32_t x1,
                                       uint32_t &o0, uint32_t &o1) {
  uint32_t ks2 = k0 ^ k1 ^ 0x1BD11BDAu;
  x0 += k0; x1 += k1;
#define TFR(r) { x0 += x1; x1 = (x1 << r) | (x1 >> (32 - r)); x1 ^= x0; }
  TFR(13) TFR(15) TFR(26) TFR(6)
  x0 += k1;  x1 += ks2 + 1u;
  TFR(17) TFR(29) TFR(16) TFR(24)
  x0 += ks2; x1 += k0 + 2u;
  TFR(13) TFR(15) TFR(26) TFR(6)
  x0 += k0;  x1 += k1 + 3u;
  TFR(17) TFR(29) TFR(16) TFR(24)
  x0 += k1;  x1 += ks2 + 4u;
  TFR(13) TFR(15) TFR(26) TFR(6)
  x0 += ks2; x1 += k0 + 5u;
#undef TFR
  o0 = x0; o1 = x1;
}

__device__ __forceinline__ float erfinv_xla(float x) {
  float w = -log1pf(-x * x);
  float p;
  if (w < 5.0f) {
    w = w - 2.5f;
    p = 2.81022636e-08f;
    p = fmaf(p, w, 3.43273939e-07f);
    p = fmaf(p, w, -3.5233877e-06f);
    p = fmaf(p, w, -4.39150654e-06f);
    p = fmaf(p, w, 0.00021858087f);
    p = fmaf(p, w, -0.00125372503f);
    p = fmaf(p, w, -0.00417768164f);
    p = fmaf(p, w, 0.246640727f);
    p = fmaf(p, w, 1.50140941f);
  } else {
    w = sqrtf(w) - 3.0f;
    p = -0.000200214257f;
    p = fmaf(p, w, 0.000100950558f);
    p = fmaf(p, w, 0.00134934322f);
    p = fmaf(p, w, -0.00367342844f);
    p = fmaf(p, w, 0.00573950773f);
    p = fmaf(p, w, -0.0076224613f);
    p = fmaf(p, w, 0.00943887047f);
    p = fmaf(p, w, 1.00167406f);
    p = fmaf(p, w, 2.83297682f);
  }
  return p * x;
}

__device__ __forceinline__ float sigmoid_xla(float x) {
  return 0.5f + 0.5f * tanhf(0.5f * x);
}

__device__ __forceinline__ float u01_from_bits(uint32_t bits) {
  return __uint_as_float((bits >> 9) | 0x3F800000u) - 1.0f;
}

__device__ __forceinline__ float normal_from_idx(uint32_t ka, uint32_t kb, uint32_t idx) {
  uint32_t o0, o1; tf2x32(ka, kb, 0u, idx, o0, o1);
  float f = u01_from_bits(o0 ^ o1);
  const float LO = __uint_as_float(0xBF7FFFFFu);
  float u = fmaxf(LO, f * 2.0f + LO);
  return __uint_as_float(0x3FB504F3u) * erfinv_xla(u);
}

__device__ __forceinline__ float gumbel_from_idx(uint32_t ka, uint32_t kb, uint32_t idx) {
  uint32_t o0, o1; tf2x32(ka, kb, 0u, idx, o0, o1);
  float f = u01_from_bits(o0 ^ o1);
  const float TINY = __uint_as_float(0x00800000u);
  float u = fmaxf(TINY, f + TINY);
  return -logf(-logf(u));
}

// ---------------- precompute ----------------

__global__ void darnn_p0(const float* __restrict__ W1, const float* __restrict__ Whh,
                         const float* __restrict__ varW,
                         float* __restrict__ W1hT, float* __restrict__ W1cT,
                         float* __restrict__ W1eT, float* __restrict__ WhhT,
                         float* __restrict__ varWT) {
  int bid = blockIdx.x, tid = threadIdx.x;
  if (bid < 768) {
    int part = bid >> 8, j = bid & 255;
    float v = W1[tid * 768 + part * 256 + j];
    float* dst = (part == 0) ? W1hT : (part == 1) ? W1cT : W1eT;
    dst[j * 256 + tid] = v;
  } else if (bid < 1024) {
    int j = bid - 768;
    for (int idx = tid; idx < 1024; idx += 256) {
      int h = idx >> 2, q = idx & 3;
      WhhT[j * 1024 + idx] = Whh[(q * 256 + h) * 256 + j];
    }
  } else {
    int j2 = bid - 1024;  // 0..256
    varWT[j2 * 256 + tid] = varW[tid * 257 + j2];
  }
}

__global__ void darnn_p1(const float* __restrict__ enc, const float* __restrict__ W1eT,
                         const float* __restrict__ b1, float* __restrict__ encW1) {
  int bt = blockIdx.x, tid = threadIdx.x;
  __shared__ float se[256];
  se[tid] = enc[bt * 256 + tid];
  __syncthreads();
  float acc = 0.f;
  for (int j = 0; j < 256; ++j) acc = fmaf(se[j], W1eT[j * 256 + tid], acc);
  encW1[bt * 256 + tid] = acc + b1[tid];
}

// ---------------- fused per-step kernel ----------------
// block bid: b = bid & 127, khalf = bid >> 7 in [0,4). Rows k = khalf*8 + [0,8).

__launch_bounds__(1024, 8)
__global__ void darnn_step(const float* __restrict__ enc, const float* __restrict__ yprev,
                           const float* __restrict__ W1hT, const float* __restrict__ W1cT,
                           const float* __restrict__ encW1, const float* __restrict__ W2,
                           const float* __restrict__ b2p, const float* __restrict__ fcW,
                           const float* __restrict__ fcbp, const float* __restrict__ varWT,
                           const float* __restrict__ varb, const float* __restrict__ WhhT,
                           const float* __restrict__ Wih, const float* __restrict__ bih,
                           const float* __restrict__ bhh, const float* __restrict__ decW,
                           const float* __restrict__ decbp, const float* __restrict__ pdfW,
                           const float* __restrict__ pdfbp,
                           const float* __restrict__ proj_p, const float* __restrict__ pdot_p,
                           const float* __restrict__ ytl_p,
                           const float* __restrict__ hprev, const float* __restrict__ cprev,
                           float* __restrict__ hcur, float* __restrict__ ccur,
                           float* __restrict__ proj_c, float* __restrict__ pdot_c,
                           float* __restrict__ ytl_c, float* __restrict__ ctx_g,
                           int t, uint32_t k1a, uint32_t k1b, uint32_t k2a, uint32_t k2b) {
  const int bid = blockIdx.x, tid = threadIdx.x;
  const int b = bid & 127, khalf = bid >> 7;
  const int bg = b >> 5, bloc = b & 31;
  const int h = tid & 255, kg = tid >> 8, lane = tid & 63;

  __shared__ __align__(16) float s_h[8 * 256];    // this block's 8 resampled h rows
  __shared__ float s_gp[1024], s_w[1024], s_gvals[1024];
  __shared__ int s_srck[1024];
  __shared__ float s_ytlp[32], s_den[32], s_logit[32];
  __shared__ int s_rowH[32], s_rowC[32];
  __shared__ __align__(16) float s_hm[256], s_cm[256], s_hmc[256], s_red[256], s_std[256];
  __shared__ float s_sc[32], s_beta[32];
  __shared__ float s_ytl;
  __shared__ float s_sredP[8 * 4], s_sredQ[8 * 4];

  // ---- phase 0: resample indices for step t-1 (redundant per (khalf,b)) ----
  if (t > 0) {
    if (tid < 32) s_ytlp[tid] = ytl_p[bg * 32 + tid];
    {
      int bl = tid >> 5, k = tid & 31;
      s_gp[tid] = proj_p[k * 128 + bg * 32 + bl];
    }
    __syncthreads();
    {
      int bl = tid >> 5, k = tid & 31;
      float p = s_gp[tid];
      const float* gp = s_gp + bl * 32;
      int rank = 0;
      for (int kk = 0; kk < 32; ++kk) {
        float q = gp[kk];
        rank += (q < p) || (q == p && kk < k);
      }
      s_srck[bl * 32 + rank] = k;
      float wv = expf((pdot_p[k * 128 + bg * 32 + bl] + s_ytlp[bl] * pdfW[256]) + pdfbp[0]);
      s_w[bl * 32 + rank] = wv;
    }
    __syncthreads();
    if (tid < 32) {
      float s = 0.f;
      for (int bl = 0; bl < 32; ++bl) s += s_w[bl * 32 + tid];
      s_den[tid] = s;
    }
    __syncthreads();
    if (tid < 32) s_logit[tid] = logf(s_w[bloc * 32 + tid] / s_den[tid]);
    __syncthreads();
    // parallel Gumbel values (pure function of index -> identical bits)
    {
      int ko = tid >> 5, k = tid & 31, r2 = ko * 128 + b;
      s_gvals[tid] = gumbel_from_idx(k2a, k2b, (uint32_t)(r2 * 32 + k)) + s_logit[k];
    }
    __syncthreads();
    if (tid < 32) {
      int ko = tid;
      const float* gv = s_gvals + ko * 32;
      float best = gv[0];
      int sv = 0;
      for (int k = 1; k < 32; ++k) { float v = gv[k]; if (v > best) { best = v; sv = k; } }
      s_rowH[ko] = s_srck[bloc * 32 + sv] * 128 + b;  // sorted gather for h
      s_rowC[ko] = sv * 128 + b;                      // unsorted gather for c
    }
  } else {
    if (tid < 32) {
      s_rowH[tid] = tid * 128 + b;
      s_rowC[tid] = tid * 128 + b;
    }
  }
  __syncthreads();

  // ---- means (k ascending, round-1 order) + stage this block's 8 h rows ----
  if (tid < 256) {
    float s1 = 0.f;
    for (int k0 = 0; k0 < 32; k0 += 8) {
      float hv[8];
#pragma unroll
      for (int i = 0; i < 8; ++i) hv[i] = hprev[(size_t)s_rowH[k0 + i] * 256 + tid];
#pragma unroll
      for (int i = 0; i < 8; ++i) s1 += hv[i];
    }
    s_hm[tid] = s1 * 0.03125f;
  } else if (tid < 512) {
    int j = tid & 255;
    float s2 = 0.f;
    for (int k0 = 0; k0 < 32; k0 += 8) {
      float cv[8];
#pragma unroll
      for (int i = 0; i < 8; ++i) cv[i] = cprev[(size_t)s_rowC[k0 + i] * 256 + j];
#pragma unroll
      for (int i = 0; i < 8; ++i) s2 += cv[i];
    }
    s_cm[j] = s2 * 0.03125f;
  } else {
    // stage the 8 GEMM rows into LDS (512 float4s)
    int i = tid - 512;
    int rr = i >> 6, c4 = i & 63;
    ((float4*)s_h)[i] = ((const float4*)hprev)[(size_t)s_rowH[khalf * 8 + rr] * 64 + c4];
  }
  __syncthreads();

  // ---- hmc GEMV: serial interleaved h/c chain (round-1 order), 16 loads in flight ----
  if (tid < 256) {
    float acc = 0.f;
    for (int j0 = 0; j0 < 256; j0 += 8) {
      float wh[8], wc[8];
#pragma unroll
      for (int i = 0; i < 8; ++i) {
        wh[i] = W1hT[(j0 + i) * 256 + tid];
        wc[i] = W1cT[(j0 + i) * 256 + tid];
      }
#pragma unroll
      for (int i = 0; i < 8; ++i) {
        acc = fmaf(s_hm[j0 + i], wh[i], acc);
        acc = fmaf(s_cm[j0 + i], wc[i], acc);
      }
    }
    s_hmc[tid] = acc;
  }
  __syncthreads();

  // ---- attention scores (round-1 tree): 16 waves, 2 tt each ----
  {
    int wv = tid >> 6;
    for (int tt = wv * 2; tt < wv * 2 + 2; ++tt) {
      float p = 0.f;
      for (int hh = lane; hh < 256; hh += 64)
        p += tanhf(encW1[(b * 32 + tt) * 256 + hh] + s_hmc[hh]) * W2[hh];
      for (int off = 32; off; off >>= 1) p += __shfl_down(p, off);
      if (lane == 0) s_sc[tt] = p + b2p[0];
    }
  }
  __syncthreads();
  if (tid == 0) {
    float m = s_sc[0];
    for (int k = 1; k < 32; ++k) m = fmaxf(m, s_sc[k]);
    float s = 0.f;
    for (int k = 0; k < 32; ++k) { float e = expf(s_sc[k] - m); s_beta[k] = e; s += e; }
    for (int k = 0; k < 32; ++k) s_beta[k] /= s;
  }
  __syncthreads();
  // ---- context + y_tilde (round-1 order) ----
  if (tid < 256) {
    float cx = 0.f;
    for (int tt = 0; tt < 32; ++tt) cx = fmaf(s_beta[tt], enc[(b * 32 + tt) * 256 + tid], cx);
    if (khalf == 0) ctx_g[b * 256 + tid] = cx;
    s_red[tid] = cx * fcW[tid];
  }
  __syncthreads();
  if (tid == 0) {
    // serial ascending sum, batched as float4 LDS loads (same add order)
    const float4* r4 = (const float4*)s_red;
    float s = 0.f;
    for (int i = 0; i < 64; ++i) {
      float4 v = r4[i];
      s = s + v.x; s = s + v.y; s = s + v.z; s = s + v.w;
    }
    s += yprev[b * 32 + t] * fcW[256];
    s_ytl = s + fcbp[0];
    if (khalf == 0) ytl_c[b] = s_ytl;
  }
  __syncthreads();
  // ---- var head -> std (round-1 order), 16 loads in flight ----
  if (tid < 256) {
    float v = s_ytl * varWT[tid];
    for (int j0 = 0; j0 < 256; j0 += 16) {
      float wv[16];
#pragma unroll
      for (int i = 0; i < 16; ++i) wv[i] = varWT[(1 + j0 + i) * 256 + tid];
#pragma unroll
      for (int i = 0; i < 16; ++i) v = fmaf(s_hm[j0 + i], wv[i], v);
    }
    v += varb[tid];
    s_std[tid] = fmaxf(v, 0.f) + log1pf(expf(-fabsf(v)));
  }
  __syncthreads();

  // ---- LSTM GEMM: 8 rows (k = khalf*8 + [0,8)), 2 rows/thread ----
  float ai[2], af[2], ag[2], ao[2];
#pragma unroll
  for (int r = 0; r < 2; ++r) { ai[r] = af[r] = ag[r] = ao[r] = 0.f; }
  {
    const float4* wp = (const float4*)WhhT + h;
    const float* shr = s_h + (kg * 2) * 256;
    for (int j = 0; j < 256; j += 4) {
      float4 w0 = wp[(j + 0) * 256];
      float4 w1 = wp[(j + 1) * 256];
      float4 w2 = wp[(j + 2) * 256];
      float4 w3 = wp[(j + 3) * 256];
#pragma unroll
      for (int r = 0; r < 2; ++r) {
        float4 h4 = *(const float4*)(shr + r * 256 + j);
        ai[r] = fmaf(h4.x, w0.x, ai[r]); ai[r] = fmaf(h4.y, w1.x, ai[r]);
        ai[r] = fmaf(h4.z, w2.x, ai[r]); ai[r] = fmaf(h4.w, w3.x, ai[r]);
        af[r] = fmaf(h4.x, w0.y, af[r]); af[r] = fmaf(h4.y, w1.y, af[r]);
        af[r] = fmaf(h4.z, w2.y, af[r]); af[r] = fmaf(h4.w, w3.y, af[r]);
        ag[r] = fmaf(h4.x, w0.z, ag[r]); ag[r] = fmaf(h4.y, w1.z, ag[r]);
        ag[r] = fmaf(h4.z, w2.z, ag[r]); ag[r] = fmaf(h4.w, w3.z, ag[r]);
        ao[r] = fmaf(h4.x, w0.w, ao[r]); ao[r] = fmaf(h4.y, w1.w, ao[r]);
        ao[r] = fmaf(h4.z, w2.w, ao[r]); ao[r] = fmaf(h4.w, w3.w, ao[r]);
      }
    }
  }

  const float bI = bih[h], bF = bih[256 + h], bG = bih[512 + h], bO = bih[768 + h];
  const float dI = bhh[h], dF = bhh[256 + h], dG = bhh[512 + h], dO = bhh[768 + h];
  const float wI = Wih[h], wF = Wih[256 + h], wG = Wih[512 + h], wO = Wih[768 + h];
  float hnv[2];
#pragma unroll
  for (int r = 0; r < 2; ++r) {
    int rl = kg * 2 + r;               // local row 0..7
    int k = khalf * 8 + rl, R = k * 128 + b;
    float xb = s_ytl;
    float pi = ((xb * wI + bI) + ai[r]) + dI;
    float pf = ((xb * wF + bF) + af[r]) + dF;
    float pg = ((xb * wG + bG) + ag[r]) + dG;
    float po = ((xb * wO + bO) + ao[r]) + dO;
    float c_old = cprev[(size_t)s_rowC[k] * 256 + h];
    float cn = sigmoid_xla(pf) * c_old + sigmoid_xla(pi) * tanhf(pg);
    float hn = sigmoid_xla(po) * tanhf(cn);
    float eps = normal_from_idx(k1a, k1b, (uint32_t)(R * 256 + h));
    hn = hn + eps * s_std[h];
    ccur[(size_t)R * 256 + h] = cn;
    hcur[(size_t)R * 256 + h] = hn;
    hnv[r] = hn;
  }

  const float dw = decW[h], pw = pdfW[h];
#pragma unroll
  for (int r = 0; r < 2; ++r) {
    int rl = kg * 2 + r;
    float v = hnv[r] * dw;
    for (int off = 32; off; off >>= 1) v += __shfl_down(v, off);
    if (lane == 0) s_sredP[rl * 4 + (h >> 6)] = v;
    float v2 = hnv[r] * pw;
    for (int off = 32; off; off >>= 1) v2 += __shfl_down(v2, off);
    if (lane == 0) s_sredQ[rl * 4 + (h >> 6)] = v2;
  }
  __syncthreads();
  if (tid < 8) {
    int rl = tid, k = khalf * 8 + rl;
    proj_c[k * 128 + b] = ((s_sredP[rl * 4 + 0] + s_sredP[rl * 4 + 1]) +
                           (s_sredP[rl * 4 + 2] + s_sredP[rl * 4 + 3])) + decbp[0];
  } else if (tid < 16) {
    int rl = tid - 8, k = khalf * 8 + rl;
    pdot_c[k * 128 + b] = (s_sredQ[rl * 4 + 0] + s_sredQ[rl * 4 + 1]) +
                          (s_sredQ[rl * 4 + 2] + s_sredQ[rl * 4 + 3]);
  }
}

// ---------------- epilogue: final resample + means + output head ----------------

__launch_bounds__(256)
__global__ void darnn_kout(const float* __restrict__ proj_g, const float* __restrict__ pdot_g,
                           const float* __restrict__ ytl_prev, const float* __restrict__ hprev,
                           const float* __restrict__ ctx_g, const float* __restrict__ decW,
                           const float* __restrict__ decbp, const float* __restrict__ encWo,
                           const float* __restrict__ encbo, const float* __restrict__ pdfW,
                           const float* __restrict__ pdfbp,
                           uint32_t k2a, uint32_t k2b, float* __restrict__ out) {
  const int b = blockIdx.x, tid = threadIdx.x, bg = b >> 5, bloc = b & 31;
  const int lane = tid & 63;
  __shared__ float s_gp[1024], s_w[1024];
  __shared__ int s_srck[1024];
  __shared__ float s_ytlp[32], s_den[32], s_logit[32];
  __shared__ int s_row[32];
  __shared__ float s_hm[256], s_sred[8];

  if (tid < 32) s_ytlp[tid] = ytl_prev[bg * 32 + tid];
  for (int i = tid; i < 1024; i += 256) {
    int bl = i >> 5, k = i & 31;
    s_gp[i] = proj_g[k * 128 + bg * 32 + bl];
  }
  __syncthreads();
  for (int i = tid; i < 1024; i += 256) {
    int bl = i >> 5, k = i & 31;
    float p = s_gp[i];
    const float* gp = s_gp + bl * 32;
    int rank = 0;
    for (int kk = 0; kk < 32; ++kk) {
      float q = gp[kk];
      rank += (q < p) || (q == p && kk < k);
    }
    s_srck[bl * 32 + rank] = k;
    float wv = expf((pdot_g[k * 128 + bg * 32 + bl] + s_ytlp[bl] * pdfW[256]) + pdfbp[0]);
    s_w[bl * 32 + rank] = wv;
  }
  __syncthreads();
  if (tid < 32) {
    float s = 0.f;
    for (int bl = 0; bl < 32; ++bl) s += s_w[bl * 32 + tid];
    s_den[tid] = s;
  }
  __syncthreads();
  if (tid < 32) s_logit[tid] = logf(s_w[bloc * 32 + tid] / s_den[tid]);
  __syncthreads();
  if (tid < 32) {
    int ko = tid, r2 = ko * 128 + b;
    float best = gumbel_from_idx(k2a, k2b, (uint32_t)(r2 * 32)) + s_logit[0];
    int sv = 0;
    for (int k = 1; k < 32; ++k) {
      float v = gumbel_from_idx(k2a, k2b, (uint32_t)(r2 * 32 + k)) + s_logit[k];
      if (v > best) { best = v; sv = k; }
    }
    s_row[ko] = s_srck[bloc * 32 + sv] * 128 + b;
  }
  __syncthreads();
  {
    float s1 = 0.f;
    for (int k = 0; k < 32; ++k) s1 += hprev[(size_t)s_row[k] * 256 + tid];
    s_hm[tid] = s1 * 0.03125f;
  }
  __syncthreads();
  {
    int wvi = tid >> 6;
    float v1 = s_hm[tid] * decW[tid];
    float v2 = ctx_g[b * 256 + tid] * encWo[tid];
    for (int off = 32; off; off >>= 1) { v1 += __shfl_down(v1, off); v2 += __shfl_down(v2, off); }
    if (lane == 0) { s_sred[wvi] = v1; s_sred[4 + wvi] = v2; }
  }
  __syncthreads();
  if (tid == 0) {
    float d1 = (s_sred[0] + s_sred[1]) + (s_sred[2] + s_sred[3]);
    float d2 = (s_sred[4] + s_sred[5]) + (s_sred[6] + s_sred[7]);
    out[b] = ((d1 + decbp[0]) + d2) + encbo[0];
  }
}

extern "C" void kernel_launch(void* const* d_in, const int* in_sizes, int n_in,
                              void* d_out, int out_size, void* d_ws, size_t ws_size,
                              hipStream_t stream) {
  const float* enc   = (const float*)d_in[0];
  const float* yprev = (const float*)d_in[1];
  const float* W1    = (const float*)d_in[2];
  const float* b1    = (const float*)d_in[3];
  const float* W2    = (const float*)d_in[4];
  const float* b2    = (const float*)d_in[5];
  const float* fcW   = (const float*)d_in[6];
  const float* fcb   = (const float*)d_in[7];
  const float* varW  = (const float*)d_in[8];
  const float* varb  = (const float*)d_in[9];
  const float* Wih   = (const float*)d_in[10];
  const float* Whh   = (const float*)d_in[11];
  const float* bih   = (const float*)d_in[12];
  const float* bhh   = (const float*)d_in[13];
  const float* decW  = (const float*)d_in[14];
  const float* decb  = (const float*)d_in[15];
  const float* pdfW  = (const float*)d_in[16];
  const float* pdfb  = (const float*)d_in[17];
  const float* encWo = (const float*)d_in[18];
  const float* encbo = (const float*)d_in[19];

  float* ws = (float*)d_ws;
  size_t o = 0;
  float* encW1 = ws + o; o += (size_t)Bn * Tn * Hn;    // 1,048,576
  float* W1hT  = ws + o; o += (size_t)Hn * Hn;
  float* W1cT  = ws + o; o += (size_t)Hn * Hn;
  float* W1eT  = ws + o; o += (size_t)Hn * Hn;
  float* WhhT  = ws + o; o += (size_t)Hn * 4 * Hn;     // 262,144
  float* varWT = ws + o; o += (size_t)257 * Hn;        // 65,792
  float* hbuf0 = ws + o; o += (size_t)Kn * Bn * Hn;    // ping-pong h
  float* hbuf1 = ws + o; o += (size_t)Kn * Bn * Hn;
  float* cbuf0 = ws + o; o += (size_t)Kn * Bn * Hn;    // ping-pong c
  float* cbuf1 = ws + o; o += (size_t)Kn * Bn * Hn;
  float* ytl0  = ws + o; o += 128;                     // ping-pong ytl
  float* ytl1  = ws + o; o += 128;
  float* ctx_g = ws + o; o += (size_t)Bn * Hn;
  float* proj0 = ws + o; o += 4096;                    // ping-pong proj
  float* proj1 = ws + o; o += 4096;
  float* pdot0 = ws + o; o += 4096;                    // ping-pong pdot
  float* pdot1 = ws + o; o += 4096;
  if (ws_size < o * sizeof(float)) return;

  float* hb[2] = { hbuf0, hbuf1 };
  float* cb[2] = { cbuf0, cbuf1 };
  float* yb[2] = { ytl0, ytl1 };
  float* pp[2] = { proj0, proj1 };
  float* pq[2] = { pdot0, pdot1 };

  // zero the t=0 "previous" state (parity (0+1)&1 = 1)
  hipMemsetAsync(hbuf1, 0, (size_t)Kn * Bn * Hn * sizeof(float), stream);
  hipMemsetAsync(cbuf1, 0, (size_t)Kn * Bn * Hn * sizeof(float), stream);

  darnn_p0<<<1281, 256, 0, stream>>>(W1, Whh, varW, W1hT, W1cT, W1eT, WhhT, varWT);
  darnn_p1<<<Bn * Tn, 256, 0, stream>>>(enc, W1eT, b1, encW1);

  uint32_t k2pa = 0, k2pb = 0;
  for (int t = 0; t < Tn; ++t) {
    uint32_t f0, f1, k1a, k1b, k2a, k2b;
    tf2x32(0u, 42u, 0u, (uint32_t)t, f0, f1);
    tf2x32(f0, f1, 0u, 0u, k1a, k1b);
    tf2x32(f0, f1, 0u, 1u, k2a, k2b);
    int cur = t & 1, prv = (t + 1) & 1;

    darnn_step<<<4 * Bn, 1024, 0, stream>>>(enc, yprev, W1hT, W1cT, encW1, W2, b2,
                                            fcW, fcb, varWT, varb, WhhT, Wih, bih, bhh,
                                            decW, decb, pdfW, pdfb,
                                            pp[prv], pq[prv], yb[prv], hb[prv], cb[prv],
                                            hb[cur], cb[cur], pp[cur], pq[cur], yb[cur],
                                            ctx_g, t, k1a, k1b, k2pa, k2pb);
    k2pa = k2a; k2pb = k2b;
  }

  darnn_kout<<<Bn, 256, 0, stream>>>(pp[1], pq[1], yb[1], hb[1], ctx_g,
                                     decW, decb, encWo, encbo, pdfW, pdfb,
                                     k2pa, k2pb, (float*)d_out);
}

// Round 8
// 2532.600 us; speedup vs baseline: 1.3939x; 1.3939x over previous
//
#include <hip/hip_runtime.h>
#include <cstdint>

// DA_RNN particle filter, B=128 T=32 H=256 K=32.
// Round 8: round-7 fused structure, but the LSTM GEMM weight stage rebuilt as a
// provably race-free SINGLE-buffered LDS pipeline: per 8-j tile,
//   barrier(A) -> publish tile from regs -> issue loads for next tile ->
//   barrier(B) -> pure-LDS FMA body.
// Every LDS write/read pair is barrier-separated in both directions. No LDS
// overlay (round-7's replay-only divergence implicates overlay/double-buffer);
// sampler has dedicated arrays. __launch_bounds__(1024,4): VGPR cap 128.
// ALL fp chains operand-for-operand identical to the verified bit-exact order.

#define Bn 128
#define Tn 32
#define Hn 256
#define Kn 32

__host__ __device__ inline void tf2x32(uint32_t k0, uint32_t k1, uint32_t x0, uint32_t x1,
                                       uint32_t &o0, uint32_t &o1) {
  uint32_t ks2 = k0 ^ k1 ^ 0x1BD11BDAu;
  x0 += k0; x1 += k1;
#define TFR(r) { x0 += x1; x1 = (x1 << r) | (x1 >> (32 - r)); x1 ^= x0; }
  TFR(13) TFR(15) TFR(26) TFR(6)
  x0 += k1;  x1 += ks2 + 1u;
  TFR(17) TFR(29) TFR(16) TFR(24)
  x0 += ks2; x1 += k0 + 2u;
  TFR(13) TFR(15) TFR(26) TFR(6)
  x0 += k0;  x1 += k1 + 3u;
  TFR(17) TFR(29) TFR(16) TFR(24)
  x0 += k1;  x1 += ks2 + 4u;
  TFR(13) TFR(15) TFR(26) TFR(6)
  x0 += ks2; x1 += k0 + 5u;
#undef TFR
  o0 = x0; o1 = x1;
}

__device__ __forceinline__ float erfinv_xla(float x) {
  float w = -log1pf(-x * x);
  float p;
  if (w < 5.0f) {
    w = w - 2.5f;
    p = 2.81022636e-08f;
    p = fmaf(p, w, 3.43273939e-07f);
    p = fmaf(p, w, -3.5233877e-06f);
    p = fmaf(p, w, -4.39150654e-06f);
    p = fmaf(p, w, 0.00021858087f);
    p = fmaf(p, w, -0.00125372503f);
    p = fmaf(p, w, -0.00417768164f);
    p = fmaf(p, w, 0.246640727f);
    p = fmaf(p, w, 1.50140941f);
  } else {
    w = sqrtf(w) - 3.0f;
    p = -0.000200214257f;
    p = fmaf(p, w, 0.000100950558f);
    p = fmaf(p, w, 0.00134934322f);
    p = fmaf(p, w, -0.00367342844f);
    p = fmaf(p, w, 0.00573950773f);
    p = fmaf(p, w, -0.0076224613f);
    p = fmaf(p, w, 0.00943887047f);
    p = fmaf(p, w, 1.00167406f);
    p = fmaf(p, w, 2.83297682f);
  }
  return p * x;
}

__device__ __forceinline__ float sigmoid_xla(float x) {
  return 0.5f + 0.5f * tanhf(0.5f * x);
}

__device__ __forceinline__ float u01_from_bits(uint32_t bits) {
  return __uint_as_float((bits >> 9) | 0x3F800000u) - 1.0f;
}

__device__ __forceinline__ float normal_from_idx(uint32_t ka, uint32_t kb, uint32_t idx) {
  uint32_t o0, o1; tf2x32(ka, kb, 0u, idx, o0, o1);
  float f = u01_from_bits(o0 ^ o1);
  const float LO = __uint_as_float(0xBF7FFFFFu);
  float u = fmaxf(LO, f * 2.0f + LO);
  return __uint_as_float(0x3FB504F3u) * erfinv_xla(u);
}

__device__ __forceinline__ float gumbel_from_idx(uint32_t ka, uint32_t kb, uint32_t idx) {
  uint32_t o0, o1; tf2x32(ka, kb, 0u, idx, o0, o1);
  float f = u01_from_bits(o0 ^ o1);
  const float TINY = __uint_as_float(0x00800000u);
  float u = fmaxf(TINY, f + TINY);
  return -logf(-logf(u));
}

// ---------------- precompute ----------------

__global__ void darnn_p0(const float* __restrict__ W1, const float* __restrict__ Whh,
                         const float* __restrict__ varW,
                         float* __restrict__ W1hT, float* __restrict__ W1cT,
                         float* __restrict__ W1eT, float* __restrict__ WhhT,
                         float* __restrict__ varWT) {
  int bid = blockIdx.x, tid = threadIdx.x;
  if (bid < 768) {
    int part = bid >> 8, j = bid & 255;
    float v = W1[tid * 768 + part * 256 + j];
    float* dst = (part == 0) ? W1hT : (part == 1) ? W1cT : W1eT;
    dst[j * 256 + tid] = v;
  } else if (bid < 1024) {
    int j = bid - 768;
    for (int idx = tid; idx < 1024; idx += 256) {
      int h = idx >> 2, q = idx & 3;
      WhhT[j * 1024 + idx] = Whh[(q * 256 + h) * 256 + j];
    }
  } else {
    int j2 = bid - 1024;  // 0..256
    varWT[j2 * 256 + tid] = varW[tid * 257 + j2];
  }
}

__global__ void darnn_p1(const float* __restrict__ enc, const float* __restrict__ W1eT,
                         const float* __restrict__ b1, float* __restrict__ encW1) {
  int bt = blockIdx.x, tid = threadIdx.x;
  __shared__ float se[256];
  se[tid] = enc[bt * 256 + tid];
  __syncthreads();
  float acc = 0.f;
  for (int j = 0; j < 256; ++j) acc = fmaf(se[j], W1eT[j * 256 + tid], acc);
  encW1[bt * 256 + tid] = acc + b1[tid];
}

// ---------------- fused per-step kernel ----------------
// block bid: b = bid & 127, khalf = bid >> 7 in {0,1}. Rows k = khalf*16 + [0,16).

__launch_bounds__(1024, 4)
__global__ void darnn_step(const float* __restrict__ enc, const float* __restrict__ yprev,
                           const float* __restrict__ W1hT, const float* __restrict__ W1cT,
                           const float* __restrict__ encW1, const float* __restrict__ W2,
                           const float* __restrict__ b2p, const float* __restrict__ fcW,
                           const float* __restrict__ fcbp, const float* __restrict__ varWT,
                           const float* __restrict__ varb, const float* __restrict__ WhhT,
                           const float* __restrict__ Wih, const float* __restrict__ bih,
                           const float* __restrict__ bhh, const float* __restrict__ decW,
                           const float* __restrict__ decbp, const float* __restrict__ pdfW,
                           const float* __restrict__ pdfbp,
                           const float* __restrict__ proj_p, const float* __restrict__ pdot_p,
                           const float* __restrict__ ytl_p,
                           const float* __restrict__ hprev, const float* __restrict__ cprev,
                           float* __restrict__ hcur, float* __restrict__ ccur,
                           float* __restrict__ proj_c, float* __restrict__ pdot_c,
                           float* __restrict__ ytl_c, float* __restrict__ ctx_g,
                           int t, uint32_t k1a, uint32_t k1b, uint32_t k2a, uint32_t k2b) {
  const int bid = blockIdx.x, tid = threadIdx.x;
  const int b = bid & 127, khalf = bid >> 7;
  const int bg = b >> 5, bloc = b & 31;
  const int h = tid & 255, kg = tid >> 8, lane = tid & 63;

  __shared__ __align__(16) float s_wbuf[8192];    // single 32 KB weight tile (8 j)
  __shared__ __align__(16) float s_h[16 * 256];   // this block's 16 resampled h rows
  __shared__ float s_gp[1024], s_w[1024], s_gvals[1024];
  __shared__ int s_srck[1024];
  __shared__ float s_ytlp[32], s_den[32], s_logit[32];
  __shared__ int s_rowH[32], s_rowC[32];
  __shared__ __align__(16) float s_hm[256], s_cm[256], s_hmc[256], s_red[256], s_std[256];
  __shared__ float s_sc[32], s_beta[32];
  __shared__ float s_ytl;
  __shared__ float s_sredP[16 * 4], s_sredQ[16 * 4];

  // ---- prestage weight tile 0 into registers (hidden by the head) ----
  const float4* W4 = (const float4*)WhhT;
  const int jp = tid >> 8;  // 0..3
  float4 rA = W4[jp * 256 + h];
  float4 rB = W4[(4 + jp) * 256 + h];

  // ---- phase 0: resample indices for step t-1 (redundant per (khalf,b)) ----
  if (t > 0) {
    if (tid < 32) s_ytlp[tid] = ytl_p[bg * 32 + tid];
    {
      int bl = tid >> 5, k = tid & 31;
      s_gp[tid] = proj_p[k * 128 + bg * 32 + bl];
    }
    __syncthreads();
    {
      int bl = tid >> 5, k = tid & 31;
      float p = s_gp[tid];
      const float* gp = s_gp + bl * 32;
      int rank = 0;
      for (int kk = 0; kk < 32; ++kk) {
        float q = gp[kk];
        rank += (q < p) || (q == p && kk < k);
      }
      s_srck[bl * 32 + rank] = k;
      float wv = expf((pdot_p[k * 128 + bg * 32 + bl] + s_ytlp[bl] * pdfW[256]) + pdfbp[0]);
      s_w[bl * 32 + rank] = wv;
    }
    __syncthreads();
    if (tid < 32) {
      float s = 0.f;
      for (int bl = 0; bl < 32; ++bl) s += s_w[bl * 32 + tid];
      s_den[tid] = s;
    }
    __syncthreads();
    if (tid < 32) s_logit[tid] = logf(s_w[bloc * 32 + tid] / s_den[tid]);
    __syncthreads();
    // parallel Gumbel values (pure function of index -> identical bits)
    {
      int ko = tid >> 5, k = tid & 31, r2 = ko * 128 + b;
      s_gvals[tid] = gumbel_from_idx(k2a, k2b, (uint32_t)(r2 * 32 + k)) + s_logit[k];
    }
    __syncthreads();
    if (tid < 32) {
      int ko = tid;
      const float* gv = s_gvals + ko * 32;
      float best = gv[0];
      int sv = 0;
      for (int k = 1; k < 32; ++k) { float v = gv[k]; if (v > best) { best = v; sv = k; } }
      s_rowH[ko] = s_srck[bloc * 32 + sv] * 128 + b;  // sorted gather for h
      s_rowC[ko] = sv * 128 + b;                      // unsorted gather for c
    }
  } else {
    if (tid < 32) {
      s_rowH[tid] = tid * 128 + b;
      s_rowC[tid] = tid * 128 + b;
    }
  }
  __syncthreads();

  // ---- means (k ascending, round-1 order, 8-batched loads) + stage s_h ----
  if (tid < 256) {
    float s1 = 0.f;
    for (int k0 = 0; k0 < 32; k0 += 8) {
      float hv[8];
#pragma unroll
      for (int i = 0; i < 8; ++i) hv[i] = hprev[(size_t)s_rowH[k0 + i] * 256 + tid];
#pragma unroll
      for (int i = 0; i < 8; ++i) s1 += hv[i];
    }
    s_hm[tid] = s1 * 0.03125f;
  } else if (tid < 512) {
    int j = tid & 255;
    float s2 = 0.f;
    for (int k0 = 0; k0 < 32; k0 += 8) {
      float cv[8];
#pragma unroll
      for (int i = 0; i < 8; ++i) cv[i] = cprev[(size_t)s_rowC[k0 + i] * 256 + j];
#pragma unroll
      for (int i = 0; i < 8; ++i) s2 += cv[i];
    }
    s_cm[j] = s2 * 0.03125f;
  } else {
    // stage this block's 16 GEMM rows into LDS (1024 float4s, 2 per thread)
    int i = tid - 512;                 // 0..511
    int rr = i >> 6, c4 = i & 63;
    const float4* hp4 = (const float4*)hprev;
    float4* sh4 = (float4*)s_h;
    sh4[i]       = hp4[(size_t)s_rowH[khalf * 16 + rr] * 64 + c4];
    sh4[i + 512] = hp4[(size_t)s_rowH[khalf * 16 + 8 + rr] * 64 + c4];
  }
  __syncthreads();

  // ---- hmc GEMV: serial interleaved h/c chain (round-1 order), batched loads ----
  if (tid < 256) {
    float acc = 0.f;
    for (int j0 = 0; j0 < 256; j0 += 8) {
      float wh[8], wc[8];
#pragma unroll
      for (int i = 0; i < 8; ++i) {
        wh[i] = W1hT[(j0 + i) * 256 + tid];
        wc[i] = W1cT[(j0 + i) * 256 + tid];
      }
#pragma unroll
      for (int i = 0; i < 8; ++i) {
        acc = fmaf(s_hm[j0 + i], wh[i], acc);
        acc = fmaf(s_cm[j0 + i], wc[i], acc);
      }
    }
    s_hmc[tid] = acc;
  }
  __syncthreads();

  // ---- attention scores (round-1 tree): 16 waves, 2 tt each ----
  {
    int wv = tid >> 6;
    for (int tt = wv * 2; tt < wv * 2 + 2; ++tt) {
      float p = 0.f;
      for (int hh = lane; hh < 256; hh += 64)
        p += tanhf(encW1[(b * 32 + tt) * 256 + hh] + s_hmc[hh]) * W2[hh];
      for (int off = 32; off; off >>= 1) p += __shfl_down(p, off);
      if (lane == 0) s_sc[tt] = p + b2p[0];
    }
  }
  __syncthreads();
  if (tid == 0) {
    float m = s_sc[0];
    for (int k = 1; k < 32; ++k) m = fmaxf(m, s_sc[k]);
    float s = 0.f;
    for (int k = 0; k < 32; ++k) { float e = expf(s_sc[k] - m); s_beta[k] = e; s += e; }
    for (int k = 0; k < 32; ++k) s_beta[k] /= s;
  }
  __syncthreads();
  // ---- context + y_tilde (round-1 order) ----
  if (tid < 256) {
    float cx = 0.f;
    for (int tt = 0; tt < 32; ++tt) cx = fmaf(s_beta[tt], enc[(b * 32 + tt) * 256 + tid], cx);
    if (khalf == 0) ctx_g[b * 256 + tid] = cx;
    s_red[tid] = cx * fcW[tid];
  }
  __syncthreads();
  if (tid == 0) {
    const float4* r4 = (const float4*)s_red;
    float s = 0.f;
    for (int i = 0; i < 64; ++i) {
      float4 v = r4[i];
      s = s + v.x; s = s + v.y; s = s + v.z; s = s + v.w;
    }
    s += yprev[b * 32 + t] * fcW[256];
    s_ytl = s + fcbp[0];
    if (khalf == 0) ytl_c[b] = s_ytl;
  }
  __syncthreads();
  // ---- var head -> std (round-1 order), batched loads ----
  if (tid < 256) {
    float v = s_ytl * varWT[tid];
    for (int j0 = 0; j0 < 256; j0 += 16) {
      float wv[16];
#pragma unroll
      for (int i = 0; i < 16; ++i) wv[i] = varWT[(1 + j0 + i) * 256 + tid];
#pragma unroll
      for (int i = 0; i < 16; ++i) v = fmaf(s_hm[j0 + i], wv[i], v);
    }
    v += varb[tid];
    s_std[tid] = fmaxf(v, 0.f) + log1pf(expf(-fabsf(v)));
  }
  // (no barrier needed here; the GEMM loop's first barrier (A) covers it)

  // ---- LSTM GEMM: 16 rows, 4 rows/thread, single-buffered LDS weight tiles ----
  float ai[4], af[4], ag[4], ao[4];
#pragma unroll
  for (int r = 0; r < 4; ++r) { ai[r] = af[r] = ag[r] = ao[r] = 0.f; }
  {
    float4* wb4 = (float4*)s_wbuf;
    const float* shr = s_h + (kg * 4) * 256;
    for (int it = 0; it < 32; ++it) {
      __syncthreads();                 // (A) all reads of previous tile complete
      wb4[tid] = rA;                   // publish tile it (regs loaded >=1 tile ago)
      wb4[tid + 1024] = rB;
      if (it + 1 < 32) {               // issue loads for tile it+1
        rA = W4[((it + 1) * 8 + jp) * 256 + h];
        rB = W4[((it + 1) * 8 + 4 + jp) * 256 + h];
      }
      __syncthreads();                 // (B) publication visible to all
      int j0 = it * 8;
#pragma unroll
      for (int g = 0; g < 2; ++g) {
        const float4* wg = (const float4*)s_wbuf + (g ? 1024 : 0) + h;
        float4 w0 = wg[0];
        float4 w1 = wg[256];
        float4 w2 = wg[512];
        float4 w3 = wg[768];
        int j = j0 + g * 4;
#pragma unroll
        for (int r = 0; r < 4; ++r) {
          float4 h4 = *(const float4*)(shr + r * 256 + j);
          ai[r] = fmaf(h4.x, w0.x, ai[r]); ai[r] = fmaf(h4.y, w1.x, ai[r]);
          ai[r] = fmaf(h4.z, w2.x, ai[r]); ai[r] = fmaf(h4.w, w3.x, ai[r]);
          af[r] = fmaf(h4.x, w0.y, af[r]); af[r] = fmaf(h4.y, w1.y, af[r]);
          af[r] = fmaf(h4.z, w2.y, af[r]); af[r] = fmaf(h4.w, w3.y, af[r]);
          ag[r] = fmaf(h4.x, w0.z, ag[r]); ag[r] = fmaf(h4.y, w1.z, ag[r]);
          ag[r] = fmaf(h4.z, w2.z, ag[r]); ag[r] = fmaf(h4.w, w3.z, ag[r]);
          ao[r] = fmaf(h4.x, w0.w, ao[r]); ao[r] = fmaf(h4.y, w1.w, ao[r]);
          ao[r] = fmaf(h4.z, w2.w, ao[r]); ao[r] = fmaf(h4.w, w3.w, ao[r]);
        }
      }
    }
  }
  __syncthreads();                     // reads of the last tile complete

  const float bI = bih[h], bF = bih[256 + h], bG = bih[512 + h], bO = bih[768 + h];
  const float dI = bhh[h], dF = bhh[256 + h], dG = bhh[512 + h], dO = bhh[768 + h];
  const float wI = Wih[h], wF = Wih[256 + h], wG = Wih[512 + h], wO = Wih[768 + h];
  float hnv[4];
#pragma unroll
  for (int r = 0; r < 4; ++r) {
    int rl = kg * 4 + r;               // local row 0..15
    int k = khalf * 16 + rl, R = k * 128 + b;
    float xb = s_ytl;
    float pi = ((xb * wI + bI) + ai[r]) + dI;
    float pf = ((xb * wF + bF) + af[r]) + dF;
    float pg = ((xb * wG + bG) + ag[r]) + dG;
    float po = ((xb * wO + bO) + ao[r]) + dO;
    float c_old = cprev[(size_t)s_rowC[k] * 256 + h];
    float cn = sigmoid_xla(pf) * c_old + sigmoid_xla(pi) * tanhf(pg);
    float hn = sigmoid_xla(po) * tanhf(cn);
    float eps = normal_from_idx(k1a, k1b, (uint32_t)(R * 256 + h));
    hn = hn + eps * s_std[h];
    ccur[(size_t)R * 256 + h] = cn;
    hcur[(size_t)R * 256 + h] = hn;
    hnv[r] = hn;
  }

  const float dw = decW[h], pw = pdfW[h];
#pragma unroll
  for (int r = 0; r < 4; ++r) {
    int rl = kg * 4 + r;
    float v = hnv[r] * dw;
    for (int off = 32; off; off >>= 1) v += __shfl_down(v, off);
    if (lane == 0) s_sredP[rl * 4 + (h >> 6)] = v;
    float v2 = hnv[r] * pw;
    for (int off = 32; off; off >>= 1) v2 += __shfl_down(v2, off);
    if (lane == 0) s_sredQ[rl * 4 + (h >> 6)] = v2;
  }
  __syncthreads();
  if (tid < 16) {
    int rl = tid, k = khalf * 16 + rl;
    proj_c[k * 128 + b] = ((s_sredP[rl * 4 + 0] + s_sredP[rl * 4 + 1]) +
                           (s_sredP[rl * 4 + 2] + s_sredP[rl * 4 + 3])) + decbp[0];
  } else if (tid < 32) {
    int rl = tid - 16, k = khalf * 16 + rl;
    pdot_c[k * 128 + b] = (s_sredQ[rl * 4 + 0] + s_sredQ[rl * 4 + 1]) +
                          (s_sredQ[rl * 4 + 2] + s_sredQ[rl * 4 + 3]);
  }
}

// ---------------- epilogue: final resample + means + output head ----------------

__launch_bounds__(256)
__global__ void darnn_kout(const float* __restrict__ proj_g, const float* __restrict__ pdot_g,
                           const float* __restrict__ ytl_prev, const float* __restrict__ hprev,
                           const float* __restrict__ ctx_g, const float* __restrict__ decW,
                           const float* __restrict__ decbp, const float* __restrict__ encWo,
                           const float* __restrict__ encbo, const float* __restrict__ pdfW,
                           const float* __restrict__ pdfbp,
                           uint32_t k2a, uint32_t k2b, float* __restrict__ out) {
  const int b = blockIdx.x, tid = threadIdx.x, bg = b >> 5, bloc = b & 31;
  const int lane = tid & 63;
  __shared__ float s_gp[1024], s_w[1024];
  __shared__ int s_srck[1024];
  __shared__ float s_ytlp[32], s_den[32], s_logit[32];
  __shared__ int s_row[32];
  __shared__ float s_hm[256], s_sred[8];

  if (tid < 32) s_ytlp[tid] = ytl_prev[bg * 32 + tid];
  for (int i = tid; i < 1024; i += 256) {
    int bl = i >> 5, k = i & 31;
    s_gp[i] = proj_g[k * 128 + bg * 32 + bl];
  }
  __syncthreads();
  for (int i = tid; i < 1024; i += 256) {
    int bl = i >> 5, k = i & 31;
    float p = s_gp[i];
    const float* gp = s_gp + bl * 32;
    int rank = 0;
    for (int kk = 0; kk < 32; ++kk) {
      float q = gp[kk];
      rank += (q < p) || (q == p && kk < k);
    }
    s_srck[bl * 32 + rank] = k;
    float wv = expf((pdot_g[k * 128 + bg * 32 + bl] + s_ytlp[bl] * pdfW[256]) + pdfbp[0]);
    s_w[bl * 32 + rank] = wv;
  }
  __syncthreads();
  if (tid < 32) {
    float s = 0.f;
    for (int bl = 0; bl < 32; ++bl) s += s_w[bl * 32 + tid];
    s_den[tid] = s;
  }
  __syncthreads();
  if (tid < 32) s_logit[tid] = logf(s_w[bloc * 32 + tid] / s_den[tid]);
  __syncthreads();
  if (tid < 32) {
    int ko = tid, r2 = ko * 128 + b;
    float best = gumbel_from_idx(k2a, k2b, (uint32_t)(r2 * 32)) + s_logit[0];
    int sv = 0;
    for (int k = 1; k < 32; ++k) {
      float v = gumbel_from_idx(k2a, k2b, (uint32_t)(r2 * 32 + k)) + s_logit[k];
      if (v > best) { best = v; sv = k; }
    }
    s_row[ko] = s_srck[bloc * 32 + sv] * 128 + b;
  }
  __syncthreads();
  {
    float s1 = 0.f;
    for (int k = 0; k < 32; ++k) s1 += hprev[(size_t)s_row[k] * 256 + tid];
    s_hm[tid] = s1 * 0.03125f;
  }
  __syncthreads();
  {
    int wvi = tid >> 6;
    float v1 = s_hm[tid] * decW[tid];
    float v2 = ctx_g[b * 256 + tid] * encWo[tid];
    for (int off = 32; off; off >>= 1) { v1 += __shfl_down(v1, off); v2 += __shfl_down(v2, off); }
    if (lane == 0) { s_sred[wvi] = v1; s_sred[4 + wvi] = v2; }
  }
  __syncthreads();
  if (tid == 0) {
    float d1 = (s_sred[0] + s_sred[1]) + (s_sred[2] + s_sred[3]);
    float d2 = (s_sred[4] + s_sred[5]) + (s_sred[6] + s_sred[7]);
    out[b] = ((d1 + decbp[0]) + d2) + encbo[0];
  }
}

extern "C" void kernel_launch(void* const* d_in, const int* in_sizes, int n_in,
                              void* d_out, int out_size, void* d_ws, size_t ws_size,
                              hipStream_t stream) {
  const float* enc   = (const float*)d_in[0];
  const float* yprev = (const float*)d_in[1];
  const float* W1    = (const float*)d_in[2];
  const float* b1    = (const float*)d_in[3];
  const float* W2    = (const float*)d_in[4];
  const float* b2    = (const float*)d_in[5];
  const float* fcW   = (const float*)d_in[6];
  const float* fcb   = (const float*)d_in[7];
  const float* varW  = (const float*)d_in[8];
  const float* varb  = (const float*)d_in[9];
  const float* Wih   = (const float*)d_in[10];
  const float* Whh   = (const float*)d_in[11];
  const float* bih   = (const float*)d_in[12];
  const float* bhh   = (const float*)d_in[13];
  const float* decW  = (const float*)d_in[14];
  const float* decb  = (const float*)d_in[15];
  const float* pdfW  = (const float*)d_in[16];
  const float* pdfb  = (const float*)d_in[17];
  const float* encWo = (const float*)d_in[18];
  const float* encbo = (const float*)d_in[19];

  float* ws = (float*)d_ws;
  size_t o = 0;
  float* encW1 = ws + o; o += (size_t)Bn * Tn * Hn;    // 1,048,576
  float* W1hT  = ws + o; o += (size_t)Hn * Hn;
  float* W1cT  = ws + o; o += (size_t)Hn * Hn;
  float* W1eT  = ws + o; o += (size_t)Hn * Hn;
  float* WhhT  = ws + o; o += (size_t)Hn * 4 * Hn;     // 262,144
  float* varWT = ws + o; o += (size_t)257 * Hn;        // 65,792
  float* hbuf0 = ws + o; o += (size_t)Kn * Bn * Hn;    // ping-pong h
  float* hbuf1 = ws + o; o += (size_t)Kn * Bn * Hn;
  float* cbuf0 = ws + o; o += (size_t)Kn * Bn * Hn;    // ping-pong c
  float* cbuf1 = ws + o; o += (size_t)Kn * Bn * Hn;
  float* ytl0  = ws + o; o += 128;                     // ping-pong ytl
  float* ytl1  = ws + o; o += 128;
  float* ctx_g = ws + o; o += (size_t)Bn * Hn;
  float* proj0 = ws + o; o += 4096;                    // ping-pong proj
  float* proj1 = ws + o; o += 4096;
  float* pdot0 = ws + o; o += 4096;                    // ping-pong pdot
  float* pdot1 = ws + o; o += 4096;
  if (ws_size < o * sizeof(float)) return;

  float* hb[2] = { hbuf0, hbuf1 };
  float* cb[2] = { cbuf0, cbuf1 };
  float* yb[2] = { ytl0, ytl1 };
  float* pp[2] = { proj0, proj1 };
  float* pq[2] = { pdot0, pdot1 };

  // zero the t=0 "previous" state (parity (0+1)&1 = 1)
  hipMemsetAsync(hbuf1, 0, (size_t)Kn * Bn * Hn * sizeof(float), stream);
  hipMemsetAsync(cbuf1, 0, (size_t)Kn * Bn * Hn * sizeof(float), stream);

  darnn_p0<<<1281, 256, 0, stream>>>(W1, Whh, varW, W1hT, W1cT, W1eT, WhhT, varWT);
  darnn_p1<<<Bn * Tn, 256, 0, stream>>>(enc, W1eT, b1, encW1);

  uint32_t k2pa = 0, k2pb = 0;
  for (int t = 0; t < Tn; ++t) {
    uint32_t f0, f1, k1a, k1b, k2a, k2b;
    tf2x32(0u, 42u, 0u, (uint32_t)t, f0, f1);
    tf2x32(f0, f1, 0u, 0u, k1a, k1b);
    tf2x32(f0, f1, 0u, 1u, k2a, k2b);
    int cur = t & 1, prv = (t + 1) & 1;

    darnn_step<<<2 * Bn, 1024, 0, stream>>>(enc, yprev, W1hT, W1cT, encW1, W2, b2,
                                            fcW, fcb, varWT, varb, WhhT, Wih, bih, bhh,
                                            decW, decb, pdfW, pdfb,
                                            pp[prv], pq[prv], yb[prv], hb[prv], cb[prv],
                                            hb[cur], cb[cur], pp[cur], pq[cur], yb[cur],
                                            ctx_g, t, k1a, k1b, k2pa, k2pb);
    k2pa = k2a; k2pb = k2b;
  }

  darnn_kout<<<Bn, 256, 0, stream>>>(pp[1], pq[1], yb[1], hb[1], ctx_g,
                                     decW, decb, encWo, encbo, pdfW, pdfb,
                                     k2pa, k2pb, (float*)d_out);
}